// Round 10
// baseline (224.069 us; speedup 1.0000x reference)
//
#include <hip/hip_runtime.h>
#include <stdint.h>

#define NPIX 4096
#define LOG2E 1.44269504088896340736f

typedef __bf16 bf16x8 __attribute__((ext_vector_type(8)));
typedef float  f32x4  __attribute__((ext_vector_type(4)));
typedef unsigned long long ull;

union FragU {
  bf16x8 f;
  uint4  u;
  ull    q[2];
  unsigned short s[8];
};

static __device__ __forceinline__ unsigned short f2bf(float x) {
  unsigned int u = __float_as_uint(x);
  u += 0x7FFFu + ((u >> 16) & 1u);
  return (unsigned short)(u >> 16);
}
static __device__ __forceinline__ float bf2f(unsigned short s) {
  return __uint_as_float(((unsigned int)s) << 16);
}
static __device__ __forceinline__ unsigned int pack2(unsigned short a, unsigned short b) {
  return (unsigned int)a | ((unsigned int)b << 16);
}
static __device__ __forceinline__ float e2(float x) { return __builtin_amdgcn_exp2f(x); }

// Global-memory fragment load (16x16x32 A/B layout: 8B at byteOff, 8B at +32).
// VERIFIED layout (rounds 1-2-5..9, absmax 0.5).
static __device__ __forceinline__ bf16x8 load_frag(const unsigned short* base, int byteOff) {
  const char* p = reinterpret_cast<const char*>(base) + byteOff;
  uint2 a = *reinterpret_cast<const uint2*>(p);
  uint2 b = *reinterpret_cast<const uint2*>(p + 32);
  FragU fu;
  fu.u = make_uint4(a.x, a.y, b.x, b.y);
  return fu.f;
}

// 8B-block swizzle (rounds 8-9, verified correct; conflicts are ~7% of cycles
// and NOT the bottleneck -- kept as-is).
static __device__ __forceinline__ int pib(int row, int beta) {
  return ((beta + 2 * (row & 7)) & 15) ^ ((row >> 3) & 1);
}

static __device__ __forceinline__ bf16x8 lds_frag(const char* base, int row, int cb) {
  const int rb = row << 7;
  ull a = *reinterpret_cast<const ull*>(base + rb + (pib(row, cb >> 3) << 3));
  ull b = *reinterpret_cast<const ull*>(base + rb + (pib(row, (cb + 32) >> 3) << 3));
  FragU fu;
  fu.q[0] = a; fu.q[1] = b;
  return fu.f;
}

static __device__ __forceinline__ void stage_write(char* dst, int t, uint4 r0, uint4 r1) {
  const int o0 = t * 16, o1 = 4096 + t * 16;
  const int w0 = o0 >> 7, w1 = o1 >> 7;
  const int e0 = ((((o0 & 127) >> 3) + 2 * (w0 & 7)) & 15);
  const int e1 = ((((o1 & 127) >> 3) + 2 * (w1 & 7)) & 15);
  const uint4 a0 = ((w0 >> 3) & 1) ? make_uint4(r0.z, r0.w, r0.x, r0.y) : r0;
  const uint4 a1 = ((w1 >> 3) & 1) ? make_uint4(r1.z, r1.w, r1.x, r1.y) : r1;
  *reinterpret_cast<uint4*>(dst + (w0 << 7) + (e0 << 3)) = a0;
  *reinterpret_cast<uint4*>(dst + (w1 << 7) + (e1 << 3)) = a1;
}

// ---------------------------------------------------------------------------
// Kernel 1: q,k,v = 1x1 conv.  qT,kT (B,N,64) bf16; v (B,64,N). q *= LOG2E.
// VERBATIM rounds 8-9 (verified).
// ---------------------------------------------------------------------------
__global__ __launch_bounds__(256) void qkv_proj(
    const float* __restrict__ x,
    const float* __restrict__ Wq, const float* __restrict__ bq,
    const float* __restrict__ Wk, const float* __restrict__ bk,
    const float* __restrict__ Wv, const float* __restrict__ bv,
    unsigned short* __restrict__ qT, unsigned short* __restrict__ kT,
    unsigned short* __restrict__ vC)
{
  const int t  = threadIdx.x;
  const int b  = blockIdx.y;
  const int n  = blockIdx.x * 256 + t;
  const int o0 = blockIdx.z * 16;

  float xv[64];
  #pragma unroll
  for (int c = 0; c < 64; ++c) xv[c] = x[((size_t)b * 64 + c) * NPIX + n];

  const float* Wp[3] = {Wq, Wk, Wv};
  const float* Bp[3] = {bq, bk, bv};

  #pragma unroll
  for (int p = 0; p < 3; ++p) {
    const float* W  = Wp[p];
    const float* Bv = Bp[p];
    unsigned short outv[16];
    #pragma unroll
    for (int oo = 0; oo < 16; ++oo) {
      float acc = Bv[o0 + oo];
      #pragma unroll
      for (int c = 0; c < 64; ++c) acc += W[(o0 + oo) * 64 + c] * xv[c];
      if (p == 0) acc *= LOG2E;
      outv[oo] = f2bf(acc);
    }
    if (p < 2) {
      unsigned short* dst = (p == 0 ? qT : kT) + ((size_t)b * NPIX + n) * 64 + o0;
      uint4 w0 = make_uint4(pack2(outv[0], outv[1]),  pack2(outv[2], outv[3]),
                            pack2(outv[4], outv[5]),  pack2(outv[6], outv[7]));
      uint4 w1 = make_uint4(pack2(outv[8], outv[9]),  pack2(outv[10], outv[11]),
                            pack2(outv[12], outv[13]), pack2(outv[14], outv[15]));
      *reinterpret_cast<uint4*>(dst)     = w0;
      *reinterpret_cast<uint4*>(dst + 8) = w1;
    } else {
      #pragma unroll
      for (int oo = 0; oo < 16; ++oo)
        vC[((size_t)b * 64 + o0 + oo) * NPIX + n] = outv[oo];
    }
  }
}

// ---------------------------------------------------------------------------
// Kernel 2: Zpart[part][b][j] = sum over part's i of 2^(q'_j . k_i).
// Round-9 math; SINGLE-barrier double-buffer loop (one __syncthreads per tile:
// iter t reads buf[t&1] then writes buf[(t+1)&1]; the top-of-iter barrier
// separates iter t-1 reads from iter t's write of the same buffer).
// ---------------------------------------------------------------------------
__global__ __launch_bounds__(256, 2) void attn_rowsum(
    const unsigned short* __restrict__ qT, const unsigned short* __restrict__ kT,
    float* __restrict__ Zpart, int ntiles)
{
  __shared__ __align__(16) char sK[2 * 8192];

  const int t    = threadIdx.x;
  const int b    = blockIdx.y;
  const int part = blockIdx.z;
  const int lane = t & 63;
  const int wv   = t >> 6;
  const int j0   = blockIdx.x * 256 + wv * 64;
  const int lr   = lane & 15;
  const int lg   = lane >> 4;

  bf16x8 aq0[4], aq1[4];
  #pragma unroll
  for (int f = 0; f < 4; ++f) {
    const unsigned short* qrow = qT + ((size_t)b * NPIX + j0 + f * 16 + lr) * 64;
    aq0[f] = load_frag(qrow, lg * 8);
    aq1[f] = load_frag(qrow, 64 + lg * 8);
  }

  const char* kbase = reinterpret_cast<const char*>(kT) + (size_t)b * NPIX * 128
                      + (size_t)part * ntiles * 8192;

  float zacc[4][4];
  #pragma unroll
  for (int f = 0; f < 4; ++f)
    #pragma unroll
    for (int r = 0; r < 4; ++r) zacc[f][r] = 0.f;

  // prologue: stage tile 0, then prefetch tile 1 into regs
  uint4 r0 = *reinterpret_cast<const uint4*>(kbase + t * 16);
  uint4 r1 = *reinterpret_cast<const uint4*>(kbase + 4096 + t * 16);
  stage_write(sK, t, r0, r1);
  if (ntiles > 1) {
    r0 = *reinterpret_cast<const uint4*>(kbase + 8192 + t * 16);
    r1 = *reinterpret_cast<const uint4*>(kbase + 8192 + 4096 + t * 16);
  }

  for (int tile = 0; tile < ntiles; ++tile) {
    __syncthreads();
    const char* buf = sK + (tile & 1) * 8192;
    bf16x8 kf0[4], kf1[4];
    #pragma unroll
    for (int s = 0; s < 4; ++s) {
      kf0[s] = lds_frag(buf, s * 16 + lr, lg * 8);
      kf1[s] = lds_frag(buf, s * 16 + lr, 64 + lg * 8);
    }
    #pragma unroll
    for (int f = 0; f < 4; ++f) {
      #pragma unroll
      for (int s = 0; s < 4; ++s) {
        f32x4 S = {0.f, 0.f, 0.f, 0.f};
        S = __builtin_amdgcn_mfma_f32_16x16x32_bf16(aq0[f], kf0[s], S, 0, 0, 0);
        S = __builtin_amdgcn_mfma_f32_16x16x32_bf16(aq1[f], kf1[s], S, 0, 0, 0);
        zacc[f][0] += e2(S[0]);
        zacc[f][1] += e2(S[1]);
        zacc[f][2] += e2(S[2]);
        zacc[f][3] += e2(S[3]);
      }
    }
    if (tile + 1 < ntiles) {
      stage_write(sK + ((tile + 1) & 1) * 8192, t, r0, r1);
      if (tile + 2 < ntiles) {
        const char* src = kbase + (size_t)(tile + 2) * 8192;
        r0 = *reinterpret_cast<const uint4*>(src + t * 16);
        r1 = *reinterpret_cast<const uint4*>(src + 4096 + t * 16);
      }
    }
  }

  #pragma unroll
  for (int f = 0; f < 4; ++f) {
    #pragma unroll
    for (int m = 8; m >= 1; m >>= 1) {
      #pragma unroll
      for (int r = 0; r < 4; ++r) zacc[f][r] += __shfl_xor(zacc[f][r], m, 64);
    }
  }
  if (lr == 0) {
    float* dst = Zpart + ((size_t)part * 8 + b) * NPIX + j0 + lg * 4;
    #pragma unroll
    for (int f = 0; f < 4; ++f) {
      #pragma unroll
      for (int r = 0; r < 4; ++r) dst[f * 16 + r] = zacc[f][r];
    }
  }
}

// ---------------------------------------------------------------------------
// Kernel 2.4: rcpZ[idx] = 1 / sum_p Zpart[p][idx], written IN-PLACE over
// Zpart[0] (thread-local read-then-write, no hazard). Round-5-verified logic.
// ---------------------------------------------------------------------------
__global__ __launch_bounds__(256) void zred(
    float* __restrict__ Zpart, int nparts)
{
  const int idx = blockIdx.x * 256 + threadIdx.x;   // b*4096 + j, 32768 total
  float z = 0.f;
  for (int p = 0; p < nparts; ++p) z += Zpart[(size_t)p * 8 * NPIX + idx];
  Zpart[idx] = 1.0f / z;
}

// ---------------------------------------------------------------------------
// Kernel 3: resP[part][b][c][i] = sum over part's j of P[j,i]*v[c,j], with
// P = 2^(q'_j.k_i) * rcpZ[j] (vscale folded in: 4 broadcast float4 loads +
// 16 muls per thread-tile). Single-barrier double-buffer loop as in rowsum.
// ---------------------------------------------------------------------------
__global__ __launch_bounds__(256, 2) void attn_pv(
    const unsigned short* __restrict__ qT, const unsigned short* __restrict__ kT,
    const unsigned short* __restrict__ vC, const float* __restrict__ rcpZ,
    unsigned short* __restrict__ resP, int ntiles)
{
  __shared__ __align__(16) char sQ[2 * 8192];
  __shared__ __align__(16) char sV[2 * 8192];

  const int t    = threadIdx.x;
  const int b    = blockIdx.y;
  const int part = blockIdx.z;
  const int lane = t & 63;
  const int wv   = t >> 6;
  const int i0   = blockIdx.x * 256 + wv * 64;
  const int lr   = lane & 15;
  const int lg   = lane >> 4;
  const int jstart = part * ntiles * 64;

  bf16x8 kf0[4], kf1[4];
  #pragma unroll
  for (int s = 0; s < 4; ++s) {
    const unsigned short* krow = kT + ((size_t)b * NPIX + i0 + s * 16 + lr) * 64;
    kf0[s] = load_frag(krow, lg * 8);
    kf1[s] = load_frag(krow, 64 + lg * 8);
  }

  const char* qbase = reinterpret_cast<const char*>(qT) + ((size_t)b * NPIX + jstart) * 128;
  const char* vbase = reinterpret_cast<const char*>(vC) + (size_t)b * 64 * 8192
                      + (size_t)jstart * 2;
  const float* rzbase = rcpZ + (size_t)b * NPIX + jstart + lg * 4;

  const int vo0_row = (t * 16) >> 7,        vo0_col = (t * 16) & 127;
  const int vo1_row = (4096 + t * 16) >> 7, vo1_col = (4096 + t * 16) & 127;

  f32x4 acc[4][4];
  #pragma unroll
  for (int m = 0; m < 4; ++m)
    #pragma unroll
    for (int s = 0; s < 4; ++s) acc[m][s] = (f32x4){0.f, 0.f, 0.f, 0.f};

  // prologue: stage tile 0, prefetch tile 1 regs
  uint4 q0 = *reinterpret_cast<const uint4*>(qbase + t * 16);
  uint4 q1 = *reinterpret_cast<const uint4*>(qbase + 4096 + t * 16);
  uint4 v0 = *reinterpret_cast<const uint4*>(vbase + (size_t)vo0_row * 8192 + vo0_col);
  uint4 v1 = *reinterpret_cast<const uint4*>(vbase + (size_t)vo1_row * 8192 + vo1_col);
  stage_write(sQ, t, q0, q1);
  stage_write(sV, t, v0, v1);
  if (ntiles > 1) {
    q0 = *reinterpret_cast<const uint4*>(qbase + 8192 + t * 16);
    q1 = *reinterpret_cast<const uint4*>(qbase + 8192 + 4096 + t * 16);
    v0 = *reinterpret_cast<const uint4*>(vbase + (size_t)vo0_row * 8192 + 128 + vo0_col);
    v1 = *reinterpret_cast<const uint4*>(vbase + (size_t)vo1_row * 8192 + 128 + vo1_col);
  }

  for (int tile = 0; tile < ntiles; ++tile) {
    __syncthreads();
    const char* Qt = sQ + (tile & 1) * 8192;
    const char* Vt = sV + (tile & 1) * 8192;

    // rcpZ for this tile's 16 (f,r) j-rows: 4 broadcast float4 loads (L1/L2)
    const float* rzt = rzbase + tile * 64;
    float4 rz0 = *reinterpret_cast<const float4*>(rzt);
    float4 rz1 = *reinterpret_cast<const float4*>(rzt + 16);
    float4 rz2 = *reinterpret_cast<const float4*>(rzt + 32);
    float4 rz3 = *reinterpret_cast<const float4*>(rzt + 48);

    bf16x8 qf0[4], qf1[4], vf0[4], vf1[4];
    #pragma unroll
    for (int f = 0; f < 4; ++f) {
      qf0[f] = lds_frag(Qt, f * 16 + lr, lg * 8);
      qf1[f] = lds_frag(Qt, f * 16 + lr, 64 + lg * 8);
    }
    #pragma unroll
    for (int m = 0; m < 4; ++m) {
      vf0[m] = lds_frag(Vt, m * 16 + lr, lg * 8);
      vf1[m] = lds_frag(Vt, m * 16 + lr, 64 + lg * 8);
    }

    #pragma unroll
    for (int s = 0; s < 4; ++s) {
      f32x4 sj[4];
      #pragma unroll
      for (int f = 0; f < 4; ++f) {
        sj[f] = (f32x4){0.f, 0.f, 0.f, 0.f};
        sj[f] = __builtin_amdgcn_mfma_f32_16x16x32_bf16(qf0[f], kf0[s], sj[f], 0, 0, 0);
        sj[f] = __builtin_amdgcn_mfma_f32_16x16x32_bf16(qf1[f], kf1[s], sj[f], 0, 0, 0);
      }
      FragU pe0, pe1;
      #pragma unroll
      for (int r = 0; r < 4; ++r) {
        pe0.f[r]     = (__bf16)(e2(sj[0][r]) * (&rz0.x)[r]);
        pe0.f[4 + r] = (__bf16)(e2(sj[1][r]) * (&rz1.x)[r]);
        pe1.f[r]     = (__bf16)(e2(sj[2][r]) * (&rz2.x)[r]);
        pe1.f[4 + r] = (__bf16)(e2(sj[3][r]) * (&rz3.x)[r]);
      }
      #pragma unroll
      for (int m = 0; m < 4; ++m) {
        acc[m][s] = __builtin_amdgcn_mfma_f32_16x16x32_bf16(vf0[m], pe0.f, acc[m][s], 0, 0, 0);
        acc[m][s] = __builtin_amdgcn_mfma_f32_16x16x32_bf16(vf1[m], pe1.f, acc[m][s], 0, 0, 0);
      }
    }

    if (tile + 1 < ntiles) {
      stage_write(sQ + ((tile + 1) & 1) * 8192, t, q0, q1);
      stage_write(sV + ((tile + 1) & 1) * 8192, t, v0, v1);
      if (tile + 2 < ntiles) {
        const char* qsrc = qbase + (size_t)(tile + 2) * 8192;
        q0 = *reinterpret_cast<const uint4*>(qsrc + t * 16);
        q1 = *reinterpret_cast<const uint4*>(qsrc + 4096 + t * 16);
        const int jb = (tile + 2) * 128;
        v0 = *reinterpret_cast<const uint4*>(vbase + (size_t)vo0_row * 8192 + jb + vo0_col);
        v1 = *reinterpret_cast<const uint4*>(vbase + (size_t)vo1_row * 8192 + jb + vo1_col);
      }
    }
  }

  unsigned short* rbase = resP + ((size_t)part * 8 + b) * 64 * NPIX;
  #pragma unroll
  for (int m = 0; m < 4; ++m) {
    #pragma unroll
    for (int s = 0; s < 4; ++s) {
      #pragma unroll
      for (int r = 0; r < 4; ++r) {
        rbase[(size_t)(m * 16 + lg * 4 + r) * NPIX + i0 + s * 16 + lr] = f2bf(acc[m][s][r]);
      }
    }
  }
}

// ---------------------------------------------------------------------------
// Kernel 3.5: res = sum_p resP (bf16 -> fp32).  VERBATIM round 9 (verified).
// ---------------------------------------------------------------------------
__global__ __launch_bounds__(256) void resred(
    const unsigned short* __restrict__ resP, float* __restrict__ res, int nparts)
{
  const size_t idx = (size_t)blockIdx.x * 256 + threadIdx.x;   // uint4 chunk
  const uint4* src = reinterpret_cast<const uint4*>(resP) + idx;
  float a[8];
  #pragma unroll
  for (int e = 0; e < 8; ++e) a[e] = 0.f;
  for (int p = 0; p < nparts; ++p) {
    FragU u;
    u.u = src[(size_t)p * 262144];
    #pragma unroll
    for (int e = 0; e < 8; ++e) a[e] += bf2f(u.s[e]);
  }
  float4 o0 = make_float4(a[0], a[1], a[2], a[3]);
  float4 o1 = make_float4(a[4], a[5], a[6], a[7]);
  reinterpret_cast<float4*>(res)[idx * 2]     = o0;
  reinterpret_cast<float4*>(res)[idx * 2 + 1] = o1;
}

// ---------------------------------------------------------------------------
// Kernel 4: out = Wo*res + bo + res.  VERBATIM rounds 6-9 (verified).
// ---------------------------------------------------------------------------
__global__ __launch_bounds__(256) void out_proj(
    const float* __restrict__ res, const float* __restrict__ Wo,
    const float* __restrict__ bo, float* __restrict__ out)
{
  const int t  = threadIdx.x;
  const int b  = blockIdx.y;
  const int n  = blockIdx.x * 256 + t;
  const int o0 = blockIdx.z * 16;

  float rv[64];
  #pragma unroll
  for (int c = 0; c < 64; ++c) rv[c] = res[((size_t)b * 64 + c) * NPIX + n];

  #pragma unroll
  for (int oo = 0; oo < 16; ++oo) {
    float acc = bo[o0 + oo];
    #pragma unroll
    for (int c = 0; c < 64; ++c) acc += Wo[(o0 + oo) * 64 + c] * rv[c];
    acc += res[((size_t)b * 64 + o0 + oo) * NPIX + n];
    out[((size_t)b * 64 + o0 + oo) * NPIX + n] = acc;
  }
}

// ---------------------------------------------------------------------------
extern "C" void kernel_launch(void* const* d_in, const int* in_sizes, int n_in,
                              void* d_out, int out_size, void* d_ws, size_t ws_size,
                              hipStream_t stream) {
  const float* x  = (const float*)d_in[0];
  const float* Wq = (const float*)d_in[1];
  const float* bq = (const float*)d_in[2];
  const float* Wk = (const float*)d_in[3];
  const float* bk = (const float*)d_in[4];
  const float* Wv = (const float*)d_in[5];
  const float* bv = (const float*)d_in[6];
  const float* Wo = (const float*)d_in[7];
  const float* bo = (const float*)d_in[8];
  float* out = (float*)d_out;

  char* ws = (char*)d_ws;
  // res (8 MB) aliases qT+kT: written by resred only after attn_pv is done.
  // rcpZ aliases Zpart[0] (zred writes it in place).
  unsigned short* qT   = (unsigned short*)(ws);                          // 4 MB
  unsigned short* kT   = (unsigned short*)(ws + ((size_t)4 << 20));      // 4 MB
  float* res           = (float*)(ws);                                   // 8 MB (alias)
  unsigned short* vC   = (unsigned short*)(ws + ((size_t)8 << 20));      // 4 MB
  float* Zpart         = (float*)(ws + ((size_t)12 << 20));              // <=1 MB
  unsigned short* resP = (unsigned short*)(ws + ((size_t)13 << 20));     // nparts*4 MB

  int nparts;
  const size_t MB = (size_t)1 << 20;
  if      (ws_size >= 13 * MB + 8 * 4 * MB) nparts = 8;   // grid 1024
  else if (ws_size >= 13 * MB + 4 * 4 * MB) nparts = 4;
  else if (ws_size >= 13 * MB + 2 * 4 * MB) nparts = 2;
  else                                      nparts = 1;
  const int ntiles = 64 / nparts;

  qkv_proj<<<dim3(16, 8, 4), 256, 0, stream>>>(x, Wq, bq, Wk, bk, Wv, bv, qT, kT, vC);
  attn_rowsum<<<dim3(16, 8, nparts), 256, 0, stream>>>(qT, kT, Zpart, ntiles);
  zred<<<dim3(128), 256, 0, stream>>>(Zpart, nparts);
  attn_pv<<<dim3(16, 8, nparts), 256, 0, stream>>>(qT, kT, vC, Zpart /*rcpZ alias*/, resP, ntiles);
  resred<<<dim3(1024), 256, 0, stream>>>(resP, res, nparts);
  out_proj<<<dim3(16, 8, 4), 256, 0, stream>>>(res, Wo, bo, out);
}